// Round 1
// baseline (298.166 us; speedup 1.0000x reference)
//
#include <hip/hip_runtime.h>
#include <hip/hip_bf16.h>

#define DEV __device__ __forceinline__

// Problem constants (fixed by the reference)
#define BATCH 2
#define SEQ   2048
#define DMODEL 1024
#define NHEAD 16
#define DK    64
#define MROWS (BATCH*SEQ)   // 4096

typedef __attribute__((ext_vector_type(4))) float f32x4;
typedef __attribute__((ext_vector_type(8))) short s16x8;
typedef __attribute__((ext_vector_type(4))) float fvec4;

// ---------------- scratch (device globals; avoids ws_size assumptions) ----
__device__ short g_Xb[MROWS*DMODEL];     // bf16 cast of current X (Q/K/V reuse)
__device__ short g_Wb[DMODEL*DMODEL];    // bf16 cast of current W (reuse)
__device__ short g_q [MROWS*DMODEL];     // [B,H,S,dk], pre-scaled by 1/8
__device__ short g_k [MROWS*DMODEL];     // [B,H,S,dk]
__device__ short g_vt[MROWS*DMODEL];     // [B,H,dk,S]  (V transposed)
__device__ short g_at[MROWS*DMODEL];     // attention out, merged [B,S,D]

DEV short f2bf(float f) {
  union { __hip_bfloat16 h; short s; } u;
  u.h = __float2bfloat16(f);
  return u.s;
}

DEV void gload_lds16(const void* g, void* l) {
  __builtin_amdgcn_global_load_lds(
      (const __attribute__((address_space(1))) void*)g,
      (__attribute__((address_space(3))) void*)l, 16, 0, 0);
}

// ---------------- fp32 -> bf16 cast, 8 elems/thread --------------------------
__global__ __launch_bounds__(256) void cast_bf16(const float* __restrict__ in,
                                                 short* __restrict__ out, int n8) {
  int i = blockIdx.x * 256 + threadIdx.x;
  if (i < n8) {
    const fvec4* p = (const fvec4*)(in + (size_t)i*8);
    fvec4 v0 = p[0], v1 = p[1];
    s16x8 r;
    r[0]=f2bf(v0[0]); r[1]=f2bf(v0[1]); r[2]=f2bf(v0[2]); r[3]=f2bf(v0[3]);
    r[4]=f2bf(v1[0]); r[5]=f2bf(v1[1]); r[6]=f2bf(v1[2]); r[7]=f2bf(v1[3]);
    *(s16x8*)(out + (size_t)i*8) = r;
  }
}

// ---------------- GEMM: C = A[M,K] * B[N,K]^T + bias -------------------------
// 128x128 tile, BK=32, 4 waves (each 64x64), 16x16x32 bf16 MFMA (m97 structure).
// MODE 1: bf16 head-split [B,H,S,dk];  MODE 2: bf16 V^T [B,H,dk,S];
// MODE 3: fp32 merged [M,N].
template<int MODE>
__global__ __launch_bounds__(256, 2)
void gemm_bt(const short* __restrict__ A, const short* __restrict__ Bw,
             const float* __restrict__ bias, void* __restrict__ outp,
             int Kdim, float scale) {
  __shared__ short As[128*32];
  __shared__ short Bs[128*32];
  const int t = threadIdx.x;
  const int l = t & 63, w = t >> 6;
  const int wr = w >> 1, wc = w & 1;
  const int rowBase = blockIdx.y * 128;
  const int colBase = blockIdx.x * 128;

  f32x4 acc[4][4] = {};

  for (int k0 = 0; k0 < Kdim; k0 += 32) {
    __syncthreads();
#pragma unroll
    for (int j = 0; j < 2; ++j) {
      int e = w*1024 + j*512 + l*8;     // linear elem in 128x32 tile
      int r = e >> 5, c = e & 31;
      gload_lds16(A  + (size_t)(rowBase + r)*Kdim + k0 + c, &As[w*1024 + j*512]);
      gload_lds16(Bw + (size_t)(colBase + r)*Kdim + k0 + c, &Bs[w*1024 + j*512]);
    }
    __syncthreads();
    s16x8 a[4], b[4];
#pragma unroll
    for (int i = 0; i < 4; ++i) {
      a[i] = *(const s16x8*)&As[(wr*64 + i*16 + (l & 15))*32 + (l >> 4)*8];
      b[i] = *(const s16x8*)&Bs[(wc*64 + i*16 + (l & 15))*32 + (l >> 4)*8];
    }
#pragma unroll
    for (int i = 0; i < 4; ++i)
#pragma unroll
      for (int jn = 0; jn < 4; ++jn)
        acc[i][jn] = __builtin_amdgcn_mfma_f32_16x16x32_bf16(a[i], b[jn], acc[i][jn], 0, 0, 0);
  }

  // epilogue: C/D layout col = l&15, row = (l>>4)*4 + r   [verified m89/m91]
#pragma unroll
  for (int i = 0; i < 4; ++i) {
    int mrow0 = rowBase + wr*64 + i*16 + (l >> 4)*4;
#pragma unroll
    for (int jn = 0; jn < 4; ++jn) {
      int n = colBase + wc*64 + jn*16 + (l & 15);
      float bv = bias[n];
#pragma unroll
      for (int r = 0; r < 4; ++r) {
        int m = mrow0 + r;
        float val = (acc[i][jn][r] + bv) * scale;
        if (MODE == 1) {
          int b = m >> 11, s = m & 2047, h = n >> 6, d = n & 63;
          ((short*)outp)[(((size_t)(b*NHEAD + h)*SEQ + s)*DK) + d] = f2bf(val);
        } else if (MODE == 2) {
          int b = m >> 11, s = m & 2047, h = n >> 6, d = n & 63;
          ((short*)outp)[((size_t)(b*NHEAD + h)*DK + d)*SEQ + s] = f2bf(val);
        } else {
          ((float*)outp)[(size_t)m*DMODEL + n] = val;
        }
      }
    }
  }
}

// ---------------- flash attention ------------------------------------------
// grid (S/64, B*H). 4 waves/block, each wave owns 16 q-rows: private softmax,
// no cross-wave reduce. KBLK=64 per iteration. q pre-scaled by 1/sqrt(dk).
__global__ __launch_bounds__(256, 2)
void attn_kernel(const short* __restrict__ qh, const short* __restrict__ kh,
                 const short* __restrict__ vt, short* __restrict__ aout) {
  __shared__ short qs[64*64];
  __shared__ short ks[64*64];
  __shared__ short vs[64*64];       // Vt tile: [d=64][s=64]
  __shared__ short Ps[4][16*64];

  const int t = threadIdx.x, l = t & 63, w = t >> 6;
  const int bh = blockIdx.y;
  const int qbase = blockIdx.x * 64;
  const size_t hoff = (size_t)bh * SEQ * DK;

  { // stage q tile (contiguous 8KB)
    const short* src = qh + hoff + (size_t)qbase*DK;
#pragma unroll
    for (int j = 0; j < 2; ++j)
      gload_lds16(src + w*1024 + j*512 + l*8, &qs[w*1024 + j*512]);
  }
  __syncthreads();
  s16x8 qf[2];
#pragma unroll
  for (int kf = 0; kf < 2; ++kf)
    qf[kf] = *(const s16x8*)&qs[(w*16 + (l & 15))*64 + kf*32 + (l >> 4)*8];

  float mrun[4], lrun[4];
  f32x4 o[4] = {};
#pragma unroll
  for (int r = 0; r < 4; ++r) { mrun[r] = -1e30f; lrun[r] = 0.f; }

  for (int kt = 0; kt < SEQ; kt += 64) {
    __syncthreads();
    { // stage K tile (contiguous) and Vt tile (row-strided)
      const short* ksrc = kh + hoff + (size_t)kt*DK;
#pragma unroll
      for (int j = 0; j < 2; ++j) {
        int e = w*1024 + j*512 + l*8;
        gload_lds16(ksrc + e, &ks[w*1024 + j*512]);
        int d = e >> 6, c = e & 63;
        gload_lds16(vt + hoff + (size_t)d*SEQ + kt + c, &vs[w*1024 + j*512]);
      }
    }
    __syncthreads();

    // QK^T: scores [16 rows][64 cols] per wave
    f32x4 sc[4] = {};
#pragma unroll
    for (int ni = 0; ni < 4; ++ni)
#pragma unroll
      for (int kf = 0; kf < 2; ++kf) {
        s16x8 bfr = *(const s16x8*)&ks[(ni*16 + (l & 15))*64 + kf*32 + (l >> 4)*8];
        sc[ni] = __builtin_amdgcn_mfma_f32_16x16x32_bf16(qf[kf], bfr, sc[ni], 0, 0, 0);
      }

    // online softmax; lane holds rows (l>>4)*4+r, cols l&15 + 16*ni
    float mnew[4], alpha[4];
#pragma unroll
    for (int r = 0; r < 4; ++r) {
      float mt = fmaxf(fmaxf(sc[0][r], sc[1][r]), fmaxf(sc[2][r], sc[3][r]));
#pragma unroll
      for (int off = 8; off; off >>= 1) mt = fmaxf(mt, __shfl_xor(mt, off));
      mnew[r] = fmaxf(mrun[r], mt);
      alpha[r] = __expf(mrun[r] - mnew[r]);
    }
    float p[4][4];
#pragma unroll
    for (int ni = 0; ni < 4; ++ni)
#pragma unroll
      for (int r = 0; r < 4; ++r)
        p[ni][r] = __expf(sc[ni][r] - mnew[r]);
#pragma unroll
    for (int r = 0; r < 4; ++r) {
      float s = p[0][r] + p[1][r] + p[2][r] + p[3][r];
#pragma unroll
      for (int off = 8; off; off >>= 1) s += __shfl_xor(s, off);
      lrun[r] = lrun[r]*alpha[r] + s;
      mrun[r] = mnew[r];
    }
    // P -> LDS (bf16), transposing C-layout -> A-layout
#pragma unroll
    for (int ni = 0; ni < 4; ++ni)
#pragma unroll
      for (int r = 0; r < 4; ++r)
        Ps[w][((l >> 4)*4 + r)*64 + ni*16 + (l & 15)] = f2bf(p[ni][r]);
    __syncthreads();   // orders Ps write->read (and is uniform)

    // rescale O
#pragma unroll
    for (int nd = 0; nd < 4; ++nd)
#pragma unroll
      for (int r = 0; r < 4; ++r)
        o[nd][r] *= alpha[r];

    s16x8 pa[2];
#pragma unroll
    for (int kf = 0; kf < 2; ++kf)
      pa[kf] = *(const s16x8*)&Ps[w][(l & 15)*64 + kf*32 + (l >> 4)*8];

    // PV: O += P[16,64] x V[64,64]  (B-operand from Vt rows, contiguous)
#pragma unroll
    for (int nd = 0; nd < 4; ++nd)
#pragma unroll
      for (int kf = 0; kf < 2; ++kf) {
        s16x8 bfr = *(const s16x8*)&vs[(nd*16 + (l & 15))*64 + kf*32 + (l >> 4)*8];
        o[nd] = __builtin_amdgcn_mfma_f32_16x16x32_bf16(pa[kf], bfr, o[nd], 0, 0, 0);
      }
  }

  // write merged [B,S,D] bf16
  int b = bh >> 4, h = bh & 15;
#pragma unroll
  for (int nd = 0; nd < 4; ++nd) {
    int dcol = h*DK + nd*16 + (l & 15);
#pragma unroll
    for (int r = 0; r < 4; ++r) {
      int srow = qbase + w*16 + (l >> 4)*4 + r;
      float val = o[nd][r] / lrun[r];
      aout[((size_t)(b*SEQ + srow))*DMODEL + dcol] = f2bf(val);
    }
  }
}

// ---------------- host side -------------------------------------------------
extern "C" void kernel_launch(void* const* d_in, const int* in_sizes, int n_in,
                              void* d_out, int out_size, void* d_ws, size_t ws_size,
                              hipStream_t stream) {
  const float* Q  = (const float*)d_in[0];
  const float* K  = (const float*)d_in[1];
  const float* V  = (const float*)d_in[2];
  const float* Wq = (const float*)d_in[3];
  const float* bq = (const float*)d_in[4];
  const float* Wk = (const float*)d_in[5];
  const float* bk = (const float*)d_in[6];
  const float* Wv = (const float*)d_in[7];
  const float* bv = (const float*)d_in[8];
  const float* Wo = (const float*)d_in[9];
  const float* bo = (const float*)d_in[10];

  short *pXb, *pWb, *pq, *pk, *pvt, *pat;
  hipGetSymbolAddress((void**)&pXb, HIP_SYMBOL(g_Xb));
  hipGetSymbolAddress((void**)&pWb, HIP_SYMBOL(g_Wb));
  hipGetSymbolAddress((void**)&pq,  HIP_SYMBOL(g_q));
  hipGetSymbolAddress((void**)&pk,  HIP_SYMBOL(g_k));
  hipGetSymbolAddress((void**)&pvt, HIP_SYMBOL(g_vt));
  hipGetSymbolAddress((void**)&pat, HIP_SYMBOL(g_at));

  const int nX8 = MROWS*DMODEL/8;     // 524288
  const int nW8 = DMODEL*DMODEL/8;    // 131072
  dim3 blk(256);
  dim3 gX((nX8 + 255)/256), gW((nW8 + 255)/256);
  dim3 gG(DMODEL/128, MROWS/128);     // (8, 32)
  dim3 gA(SEQ/64, BATCH*NHEAD);       // (32, 32)

  // q projection (scale 1/sqrt(dk) folded in)
  cast_bf16<<<gX, blk, 0, stream>>>(Q,  pXb, nX8);
  cast_bf16<<<gW, blk, 0, stream>>>(Wq, pWb, nW8);
  gemm_bt<1><<<gG, blk, 0, stream>>>(pXb, pWb, bq, pq, DMODEL, 0.125f);
  // k projection
  cast_bf16<<<gX, blk, 0, stream>>>(K,  pXb, nX8);
  cast_bf16<<<gW, blk, 0, stream>>>(Wk, pWb, nW8);
  gemm_bt<1><<<gG, blk, 0, stream>>>(pXb, pWb, bk, pk, DMODEL, 1.0f);
  // v projection (writes V^T layout)
  cast_bf16<<<gX, blk, 0, stream>>>(V,  pXb, nX8);
  cast_bf16<<<gW, blk, 0, stream>>>(Wv, pWb, nW8);
  gemm_bt<2><<<gG, blk, 0, stream>>>(pXb, pWb, bv, pvt, DMODEL, 1.0f);
  // attention
  attn_kernel<<<gA, blk, 0, stream>>>(pq, pk, pvt, pat);
  // output projection -> fp32 d_out
  cast_bf16<<<gW, blk, 0, stream>>>(Wo, pWb, nW8);
  gemm_bt<3><<<gG, blk, 0, stream>>>(pat, pWb, bo, (float*)d_out, DMODEL, 1.0f);
}

// Round 2
// 206.914 us; speedup vs baseline: 1.4410x; 1.4410x over previous
//
#include <hip/hip_runtime.h>
#include <hip/hip_bf16.h>

#define DEV __device__ __forceinline__

#define BATCH 2
#define SEQ   2048
#define DMODEL 1024
#define NHEAD 16
#define DK    64
#define MROWS (BATCH*SEQ)   // 4096

typedef __attribute__((ext_vector_type(4))) float f32x4;
typedef __attribute__((ext_vector_type(8))) short s16x8;
typedef __attribute__((ext_vector_type(4))) float fvec4;

// ---------------- scratch (device globals) ---------------------------------
__device__ short g_X[3][MROWS*DMODEL];   // bf16 Q,K,V inputs
__device__ short g_W[4][DMODEL*DMODEL];  // bf16 Wq,Wk,Wv,Wo
__device__ short g_q [MROWS*DMODEL];     // [B,H,S,dk], pre-scaled by 1/8
__device__ short g_k [MROWS*DMODEL];     // [B,H,S,dk]
__device__ short g_vt[MROWS*DMODEL];     // [B,H,dk,S]
__device__ short g_at[MROWS*DMODEL];     // attention out [B,S,D]

DEV short f2bf(float f) {
  union { __hip_bfloat16 h; short s; } u;
  u.h = __float2bfloat16(f);
  return u.s;
}

DEV void gload_lds16(const void* g, void* l) {
  __builtin_amdgcn_global_load_lds(
      (const __attribute__((address_space(1))) void*)g,
      (__attribute__((address_space(3))) void*)l, 16, 0, 0);
}

// ---------------- fused fp32 -> bf16 casts ---------------------------------
__global__ __launch_bounds__(256) void cast3(const float* __restrict__ a,
                                             const float* __restrict__ b,
                                             const float* __restrict__ c, int n8) {
  const float* src = blockIdx.z == 0 ? a : blockIdx.z == 1 ? b : c;
  short* dst = g_X[blockIdx.z];
  int i = blockIdx.x * 256 + threadIdx.x;
  if (i < n8) {
    const fvec4* p = (const fvec4*)(src + (size_t)i*8);
    fvec4 v0 = p[0], v1 = p[1];
    s16x8 r;
    r[0]=f2bf(v0[0]); r[1]=f2bf(v0[1]); r[2]=f2bf(v0[2]); r[3]=f2bf(v0[3]);
    r[4]=f2bf(v1[0]); r[5]=f2bf(v1[1]); r[6]=f2bf(v1[2]); r[7]=f2bf(v1[3]);
    *(s16x8*)(dst + (size_t)i*8) = r;
  }
}

__global__ __launch_bounds__(256) void cast4(const float* __restrict__ a,
                                             const float* __restrict__ b,
                                             const float* __restrict__ c,
                                             const float* __restrict__ d, int n8) {
  const float* src = blockIdx.z == 0 ? a : blockIdx.z == 1 ? b
                   : blockIdx.z == 2 ? c : d;
  short* dst = g_W[blockIdx.z];
  int i = blockIdx.x * 256 + threadIdx.x;
  if (i < n8) {
    const fvec4* p = (const fvec4*)(src + (size_t)i*8);
    fvec4 v0 = p[0], v1 = p[1];
    s16x8 r;
    r[0]=f2bf(v0[0]); r[1]=f2bf(v0[1]); r[2]=f2bf(v0[2]); r[3]=f2bf(v0[3]);
    r[4]=f2bf(v1[0]); r[5]=f2bf(v1[1]); r[6]=f2bf(v1[2]); r[7]=f2bf(v1[3]);
    *(s16x8*)(dst + (size_t)i*8) = r;
  }
}

// ---------------- GEMM core: C = A[M,K] * B[N,K]^T + bias ------------------
// 128x128 tile, BK=32, 4 waves, double-buffered 2-phase prefetch,
// swizzled LDS (^((row&3)<<3) on short index; 8-way -> 4-way conflicts).
struct GemmSmem { short As[2][128*32]; short Bs[2][128*32]; };

DEV void gemm_core(GemmSmem& sm, const short* __restrict__ A,
                   const short* __restrict__ Bw, const float* __restrict__ bias,
                   void* __restrict__ outp, float scale, int mode,
                   int rowBase, int colBase) {
  const int t = threadIdx.x, l = t & 63, w = t >> 6, g = l >> 4;
  const int wr = w >> 1, wc = w & 1;
  const int Kdim = DMODEL;

  f32x4 acc[4][4] = {};

  auto stage = [&](int buf, int k0) {
#pragma unroll
    for (int j = 0; j < 2; ++j) {
      int e = w*1024 + j*512 + l*8;
      int e2 = e ^ (((e >> 5) & 3) << 3);      // pre-swizzled source
      int r = e2 >> 5, c = e2 & 31;
      gload_lds16(A  + (size_t)(rowBase + r)*Kdim + k0 + c, &sm.As[buf][w*1024 + j*512]);
      gload_lds16(Bw + (size_t)(colBase + r)*Kdim + k0 + c, &sm.Bs[buf][w*1024 + j*512]);
    }
  };

  stage(0, 0);
  __syncthreads();

  int cur = 0;
  for (int k0 = 0; k0 < Kdim; k0 += 32) {
    if (k0 + 32 < Kdim) stage(cur ^ 1, k0 + 32);   // prefetch overlaps compute
    s16x8 a[4], b[4];
#pragma unroll
    for (int i = 0; i < 4; ++i) {
      int ra = wr*64 + i*16 + (l & 15);
      int ia = (ra*32 + g*8) ^ ((ra & 3) << 3);
      a[i] = *(const s16x8*)&sm.As[cur][ia];
      int rb = wc*64 + i*16 + (l & 15);
      int ib = (rb*32 + g*8) ^ ((rb & 3) << 3);
      b[i] = *(const s16x8*)&sm.Bs[cur][ib];
    }
    __builtin_amdgcn_s_setprio(1);
#pragma unroll
    for (int i = 0; i < 4; ++i)
#pragma unroll
      for (int jn = 0; jn < 4; ++jn)
        acc[i][jn] = __builtin_amdgcn_mfma_f32_16x16x32_bf16(a[i], b[jn], acc[i][jn], 0, 0, 0);
    __builtin_amdgcn_s_setprio(0);
    __syncthreads();      // drains prefetch vmcnt + all ds reads
    cur ^= 1;
  }

  // epilogue: C/D layout col = l&15, row = (l>>4)*4 + r
#pragma unroll
  for (int i = 0; i < 4; ++i) {
    int mrow0 = rowBase + wr*64 + i*16 + g*4;
#pragma unroll
    for (int jn = 0; jn < 4; ++jn) {
      int n = colBase + wc*64 + jn*16 + (l & 15);
      float bv = bias[n];
#pragma unroll
      for (int r = 0; r < 4; ++r) {
        int m = mrow0 + r;
        float val = (acc[i][jn][r] + bv) * scale;
        if (mode == 1) {
          int b = m >> 11, s = m & 2047, h = n >> 6, d = n & 63;
          ((short*)outp)[(((size_t)(b*NHEAD + h)*SEQ + s)*DK) + d] = f2bf(val);
        } else if (mode == 2) {
          int b = m >> 11, s = m & 2047, h = n >> 6, d = n & 63;
          ((short*)outp)[((size_t)(b*NHEAD + h)*DK + d)*SEQ + s] = f2bf(val);
        } else {
          ((float*)outp)[(size_t)m*DMODEL + n] = val;
        }
      }
    }
  }
}

// fused Q/K/V projections: grid (8, 32, 3) -> 768 blocks = 3 blocks/CU
__global__ __launch_bounds__(256, 2)
void proj_qkv(const float* __restrict__ bq, const float* __restrict__ bk,
              const float* __restrict__ bv) {
  __shared__ GemmSmem sm;
  int z = blockIdx.z;
  const float* bias = z == 0 ? bq : z == 1 ? bk : bv;
  void* outp = z == 0 ? (void*)g_q : z == 1 ? (void*)g_k : (void*)g_vt;
  gemm_core(sm, g_X[z], g_W[z], bias, outp, z == 0 ? 0.125f : 1.0f,
            z == 2 ? 2 : 1, blockIdx.y*128, blockIdx.x*128);
}

__global__ __launch_bounds__(256, 2)
void proj_out(const float* __restrict__ bo, float* __restrict__ out) {
  __shared__ GemmSmem sm;
  gemm_core(sm, g_at, g_W[3], bo, out, 1.0f, 3, blockIdx.y*128, blockIdx.x*128);
}

// ---------------- flash attention ------------------------------------------
// grid (S/64, B*H). 4 waves, 16 q-rows each. KBLK=64, double-buffered K/V
// with prefetch; all LDS tiles XOR-swizzled (^((row&7)<<3) on short idx).
// qs is reused as per-wave Ps after the prologue (no extra barrier needed).
__global__ __launch_bounds__(256, 4)
void attn_kernel(short* __restrict__ aout) {
  __shared__ short qs[64*64];       // rows w*16.. belong to wave w; reused as Ps
  __shared__ short ks[2][64*64];
  __shared__ short vs[2][64*64];

  const int t = threadIdx.x, l = t & 63, w = t >> 6, g = l >> 4;
  const int bh = blockIdx.y;
  const int qbase = blockIdx.x * 64;
  const size_t hoff = (size_t)bh * SEQ * DK;

  auto stage_kv = [&](int buf, int kt) {
#pragma unroll
    for (int j = 0; j < 2; ++j) {
      int e = w*1024 + j*512 + l*8;
      int e2 = e ^ (((e >> 6) & 7) << 3);
      gload_lds16(g_k + hoff + (size_t)kt*DK + e2, &ks[buf][w*1024 + j*512]);
      gload_lds16(g_vt + hoff + (size_t)(e2 >> 6)*SEQ + kt + (e2 & 63),
                  &vs[buf][w*1024 + j*512]);
    }
  };

  { // prologue: stage Q + first K/V tile
#pragma unroll
    for (int j = 0; j < 2; ++j) {
      int e = w*1024 + j*512 + l*8;
      int e2 = e ^ (((e >> 6) & 7) << 3);
      gload_lds16(g_q + hoff + (size_t)qbase*DK + e2, &qs[w*1024 + j*512]);
    }
    stage_kv(0, 0);
  }
  __syncthreads();

  s16x8 qf[2];
#pragma unroll
  for (int kf = 0; kf < 2; ++kf) {
    int row = w*16 + (l & 15);
    int idx = (row*64 + kf*32 + g*8) ^ ((row & 7) << 3);
    qf[kf] = *(const s16x8*)&qs[idx];
  }

  float mrun[4], lrun[4];
  f32x4 o[4] = {};
#pragma unroll
  for (int r = 0; r < 4; ++r) { mrun[r] = -1e30f; lrun[r] = 0.f; }

  int cur = 0;
  for (int kt = 0; kt < SEQ; kt += 64) {
    if (kt + 64 < SEQ) stage_kv(cur ^ 1, kt + 64);   // prefetch next tile

    // QK^T: per wave scores[16 q-rows][64 k]
    f32x4 sc[4] = {};
    __builtin_amdgcn_s_setprio(1);
#pragma unroll
    for (int ni = 0; ni < 4; ++ni)
#pragma unroll
      for (int kf = 0; kf < 2; ++kf) {
        int row = ni*16 + (l & 15);
        int idx = (row*64 + kf*32 + g*8) ^ ((row & 7) << 3);
        s16x8 bfr = *(const s16x8*)&ks[cur][idx];
        sc[ni] = __builtin_amdgcn_mfma_f32_16x16x32_bf16(qf[kf], bfr, sc[ni], 0, 0, 0);
      }
    __builtin_amdgcn_s_setprio(0);

    // online softmax: lane holds q-row g*4+r, k-col ni*16+(l&15)
    float mnew[4], alpha[4];
#pragma unroll
    for (int r = 0; r < 4; ++r) {
      float mt = fmaxf(fmaxf(sc[0][r], sc[1][r]), fmaxf(sc[2][r], sc[3][r]));
#pragma unroll
      for (int off = 8; off; off >>= 1) mt = fmaxf(mt, __shfl_xor(mt, off));
      mnew[r] = fmaxf(mrun[r], mt);
      alpha[r] = __expf(mrun[r] - mnew[r]);
    }
    float p[4][4];
#pragma unroll
    for (int ni = 0; ni < 4; ++ni)
#pragma unroll
      for (int r = 0; r < 4; ++r)
        p[ni][r] = __expf(sc[ni][r] - mnew[r]);
#pragma unroll
    for (int r = 0; r < 4; ++r) {
      float s = p[0][r] + p[1][r] + p[2][r] + p[3][r];
#pragma unroll
      for (int off = 8; off; off >>= 1) s += __shfl_xor(s, off);
      lrun[r] = lrun[r]*alpha[r] + s;
      mrun[r] = mnew[r];
    }

    // P -> wave-private LDS region (qs), swizzled; wave-local sync only
#pragma unroll
    for (int ni = 0; ni < 4; ++ni)
#pragma unroll
      for (int r = 0; r < 4; ++r) {
        int pr = g*4 + r, pc = ni*16 + (l & 15);
        int idx = (w*1024 + pr*64 + pc) ^ ((pr & 7) << 3);
        qs[idx] = f2bf(p[ni][r]);
      }
    asm volatile("s_waitcnt lgkmcnt(0)" ::: "memory");
    __builtin_amdgcn_sched_barrier(0);

    s16x8 pa[2];
#pragma unroll
    for (int kf = 0; kf < 2; ++kf) {
      int idx = (w*1024 + (l & 15)*64 + kf*32 + g*8) ^ ((l & 7) << 3);
      pa[kf] = *(const s16x8*)&qs[idx];
    }

    // rescale O, then PV
#pragma unroll
    for (int nd = 0; nd < 4; ++nd)
#pragma unroll
      for (int r = 0; r < 4; ++r)
        o[nd][r] *= alpha[r];

    __builtin_amdgcn_s_setprio(1);
#pragma unroll
    for (int nd = 0; nd < 4; ++nd)
#pragma unroll
      for (int kf = 0; kf < 2; ++kf) {
        int row = nd*16 + (l & 15);
        int idx = (row*64 + kf*32 + g*8) ^ ((row & 7) << 3);
        s16x8 bfr = *(const s16x8*)&vs[cur][idx];
        o[nd] = __builtin_amdgcn_mfma_f32_16x16x32_bf16(pa[kf], bfr, o[nd], 0, 0, 0);
      }
    __builtin_amdgcn_s_setprio(0);

    __syncthreads();      // drains prefetch; all waves done with buf[cur]
    cur ^= 1;
  }

  // write merged [B,S,D] bf16
  int b = bh >> 4, h = bh & 15;
#pragma unroll
  for (int nd = 0; nd < 4; ++nd) {
    int dcol = h*DK + nd*16 + (l & 15);
#pragma unroll
    for (int r = 0; r < 4; ++r) {
      int srow = qbase + w*16 + g*4 + r;
      float val = o[nd][r] / lrun[r];
      aout[((size_t)(b*SEQ + srow))*DMODEL + dcol] = f2bf(val);
    }
  }
}

// ---------------- host side -------------------------------------------------
extern "C" void kernel_launch(void* const* d_in, const int* in_sizes, int n_in,
                              void* d_out, int out_size, void* d_ws, size_t ws_size,
                              hipStream_t stream) {
  const float* Q  = (const float*)d_in[0];
  const float* K  = (const float*)d_in[1];
  const float* V  = (const float*)d_in[2];
  const float* bq = (const float*)d_in[4];
  const float* bk = (const float*)d_in[6];
  const float* bv = (const float*)d_in[8];
  const float* bo = (const float*)d_in[10];
  const float* Wq = (const float*)d_in[3];
  const float* Wk = (const float*)d_in[5];
  const float* Wv = (const float*)d_in[7];
  const float* Wo = (const float*)d_in[9];

  short* pat;
  hipGetSymbolAddress((void**)&pat, HIP_SYMBOL(g_at));

  const int nX8 = MROWS*DMODEL/8;     // 524288
  const int nW8 = DMODEL*DMODEL/8;    // 131072
  dim3 blk(256);

  cast3<<<dim3(nX8/256, 1, 3), blk, 0, stream>>>(Q, K, V, nX8);
  cast4<<<dim3(nW8/256, 1, 4), blk, 0, stream>>>(Wq, Wk, Wv, Wo, nW8);
  proj_qkv<<<dim3(DMODEL/128, MROWS/128, 3), blk, 0, stream>>>(bq, bk, bv);
  attn_kernel<<<dim3(SEQ/64, BATCH*NHEAD), blk, 0, stream>>>(pat);
  proj_out<<<dim3(DMODEL/128, MROWS/128), blk, 0, stream>>>(bo, (float*)d_out);
}

// Round 3
// 163.743 us; speedup vs baseline: 1.8209x; 1.2637x over previous
//
#include <hip/hip_runtime.h>
#include <hip/hip_bf16.h>

#define DEV __device__ __forceinline__

#define BATCH 2
#define SEQ   2048
#define DMODEL 1024
#define NHEAD 16
#define DK    64
#define MROWS (BATCH*SEQ)   // 4096

typedef __attribute__((ext_vector_type(4))) float f32x4;
typedef __attribute__((ext_vector_type(8))) short s16x8;
typedef __attribute__((ext_vector_type(4))) short s16x4;
typedef __attribute__((ext_vector_type(4))) float fvec4;

// ---------------- scratch (device globals) ---------------------------------
__device__ short g_X[3][MROWS*DMODEL];   // bf16 Q,K,V inputs
__device__ short g_W[4][DMODEL*DMODEL];  // bf16 Wq,Wk,Wv,Wo
__device__ short g_q [MROWS*DMODEL];     // [B,H,S,dk], pre-scaled by 1/8
__device__ short g_k [MROWS*DMODEL];     // [B,H,S,dk]
__device__ short g_vt[MROWS*DMODEL];     // [B,H,dk,S]
__device__ short g_at[MROWS*DMODEL];     // attention out [B,S,D]

DEV short f2bf(float f) {
  union { __hip_bfloat16 h; short s; } u;
  u.h = __float2bfloat16(f);
  return u.s;
}

DEV void gload_lds16(const void* g, void* l) {
  __builtin_amdgcn_global_load_lds(
      (const __attribute__((address_space(1))) void*)g,
      (__attribute__((address_space(3))) void*)l, 16, 0, 0);
}

// ---------------- fused fp32 -> bf16 casts ---------------------------------
__global__ __launch_bounds__(256) void cast3(const float* __restrict__ a,
                                             const float* __restrict__ b,
                                             const float* __restrict__ c, int n8) {
  const float* src = blockIdx.z == 0 ? a : blockIdx.z == 1 ? b : c;
  short* dst = g_X[blockIdx.z];
  int i = blockIdx.x * 256 + threadIdx.x;
  if (i < n8) {
    const fvec4* p = (const fvec4*)(src + (size_t)i*8);
    fvec4 v0 = p[0], v1 = p[1];
    s16x8 r;
    r[0]=f2bf(v0[0]); r[1]=f2bf(v0[1]); r[2]=f2bf(v0[2]); r[3]=f2bf(v0[3]);
    r[4]=f2bf(v1[0]); r[5]=f2bf(v1[1]); r[6]=f2bf(v1[2]); r[7]=f2bf(v1[3]);
    *(s16x8*)(dst + (size_t)i*8) = r;
  }
}

__global__ __launch_bounds__(256) void cast4(const float* __restrict__ a,
                                             const float* __restrict__ b,
                                             const float* __restrict__ c,
                                             const float* __restrict__ d, int n8) {
  const float* src = blockIdx.z == 0 ? a : blockIdx.z == 1 ? b
                   : blockIdx.z == 2 ? c : d;
  short* dst = g_W[blockIdx.z];
  int i = blockIdx.x * 256 + threadIdx.x;
  if (i < n8) {
    const fvec4* p = (const fvec4*)(src + (size_t)i*8);
    fvec4 v0 = p[0], v1 = p[1];
    s16x8 r;
    r[0]=f2bf(v0[0]); r[1]=f2bf(v0[1]); r[2]=f2bf(v0[2]); r[3]=f2bf(v0[3]);
    r[4]=f2bf(v1[0]); r[5]=f2bf(v1[1]); r[6]=f2bf(v1[2]); r[7]=f2bf(v1[3]);
    *(s16x8*)(dst + (size_t)i*8) = r;
  }
}

// ---------------- GEMM core: C = A[M,K] * B[N,K]^T + bias ------------------
struct GemmSmem { short As[2][128*32]; short Bs[2][128*32]; };

DEV void gemm_core(GemmSmem& sm, const short* __restrict__ A,
                   const short* __restrict__ Bw, const float* __restrict__ bias,
                   void* __restrict__ outp, float scale, int mode,
                   int rowBase, int colBase) {
  const int t = threadIdx.x, l = t & 63, w = t >> 6, g = l >> 4;
  const int wr = w >> 1, wc = w & 1;
  const int Kdim = DMODEL;

  f32x4 acc[4][4] = {};

  auto stage = [&](int buf, int k0) {
#pragma unroll
    for (int j = 0; j < 2; ++j) {
      int e = w*1024 + j*512 + l*8;
      int e2 = e ^ (((e >> 5) & 3) << 3);      // pre-swizzled source
      int r = e2 >> 5, c = e2 & 31;
      gload_lds16(A  + (size_t)(rowBase + r)*Kdim + k0 + c, &sm.As[buf][w*1024 + j*512]);
      gload_lds16(Bw + (size_t)(colBase + r)*Kdim + k0 + c, &sm.Bs[buf][w*1024 + j*512]);
    }
  };

  stage(0, 0);
  __syncthreads();

  int cur = 0;
  for (int k0 = 0; k0 < Kdim; k0 += 32) {
    if (k0 + 32 < Kdim) stage(cur ^ 1, k0 + 32);   // prefetch overlaps compute
    s16x8 a[4], b[4];
#pragma unroll
    for (int i = 0; i < 4; ++i) {
      int ra = wr*64 + i*16 + (l & 15);
      int ia = (ra*32 + g*8) ^ ((ra & 3) << 3);
      a[i] = *(const s16x8*)&sm.As[cur][ia];
      int rb = wc*64 + i*16 + (l & 15);
      int ib = (rb*32 + g*8) ^ ((rb & 3) << 3);
      b[i] = *(const s16x8*)&sm.Bs[cur][ib];
    }
    __builtin_amdgcn_s_setprio(1);
#pragma unroll
    for (int i = 0; i < 4; ++i)
#pragma unroll
      for (int jn = 0; jn < 4; ++jn)
        acc[i][jn] = __builtin_amdgcn_mfma_f32_16x16x32_bf16(a[i], b[jn], acc[i][jn], 0, 0, 0);
    __builtin_amdgcn_s_setprio(0);
    __syncthreads();
    cur ^= 1;
  }

#pragma unroll
  for (int i = 0; i < 4; ++i) {
    int mrow0 = rowBase + wr*64 + i*16 + g*4;
#pragma unroll
    for (int jn = 0; jn < 4; ++jn) {
      int n = colBase + wc*64 + jn*16 + (l & 15);
      float bv = bias[n];
#pragma unroll
      for (int r = 0; r < 4; ++r) {
        int m = mrow0 + r;
        float val = (acc[i][jn][r] + bv) * scale;
        if (mode == 1) {
          int b = m >> 11, s = m & 2047, h = n >> 6, d = n & 63;
          ((short*)outp)[(((size_t)(b*NHEAD + h)*SEQ + s)*DK) + d] = f2bf(val);
        } else if (mode == 2) {
          int b = m >> 11, s = m & 2047, h = n >> 6, d = n & 63;
          ((short*)outp)[((size_t)(b*NHEAD + h)*DK + d)*SEQ + s] = f2bf(val);
        } else {
          ((float*)outp)[(size_t)m*DMODEL + n] = val;
        }
      }
    }
  }
}

__global__ __launch_bounds__(256, 2)
void proj_qkv(const float* __restrict__ bq, const float* __restrict__ bk,
              const float* __restrict__ bv) {
  __shared__ GemmSmem sm;
  int z = blockIdx.z;
  const float* bias = z == 0 ? bq : z == 1 ? bk : bv;
  void* outp = z == 0 ? (void*)g_q : z == 1 ? (void*)g_k : (void*)g_vt;
  gemm_core(sm, g_X[z], g_W[z], bias, outp, z == 0 ? 0.125f : 1.0f,
            z == 2 ? 2 : 1, blockIdx.y*128, blockIdx.x*128);
}

__global__ __launch_bounds__(256, 2)
void proj_out(const float* __restrict__ bo, float* __restrict__ out) {
  __shared__ GemmSmem sm;
  gemm_core(sm, g_at, g_W[3], bo, out, 1.0f, 3, blockIdx.y*128, blockIdx.x*128);
}

// ---------------- flash attention (swapped QK^T, lane-local softmax) --------
// grid (S/64, B*H). 4 waves, 16 q-rows each. KBLK=64, double-buffered K/V.
// QK^T computed as mfma(K,Q) -> S[k][q]: lane owns 16 k-scores of q-row l&15.
// Softmax: in-lane reduce + 2 shfl_xor(16/32). P written as 4x ds_write_b64
// in PV A-layout. T13 defer-max skips rescale when max growth <= 8.
__global__ __launch_bounds__(256, 4)
void attn_kernel(short* __restrict__ aout) {
  __shared__ short qs[64*64];       // rows w*16..: wave-private; reused as P
  __shared__ short ks[2][64*64];
  __shared__ short vs[2][64*64];

  const int t = threadIdx.x, l = t & 63, w = t >> 6, g = l >> 4;
  const int q15 = l & 15;
  const int bh = blockIdx.y;
  const int qbase = blockIdx.x * 64;
  const size_t hoff = (size_t)bh * SEQ * DK;

  auto stage_kv = [&](int buf, int kt) {
#pragma unroll
    for (int j = 0; j < 2; ++j) {
      int e = w*1024 + j*512 + l*8;
      int e2 = e ^ (((e >> 6) & 7) << 3);
      gload_lds16(g_k + hoff + (size_t)kt*DK + e2, &ks[buf][w*1024 + j*512]);
      gload_lds16(g_vt + hoff + (size_t)(e2 >> 6)*SEQ + kt + (e2 & 63),
                  &vs[buf][w*1024 + j*512]);
    }
  };

  { // prologue: stage Q + first K/V tile
#pragma unroll
    for (int j = 0; j < 2; ++j) {
      int e = w*1024 + j*512 + l*8;
      int e2 = e ^ (((e >> 6) & 7) << 3);
      gload_lds16(g_q + hoff + (size_t)qbase*DK + e2, &qs[w*1024 + j*512]);
    }
    stage_kv(0, 0);
  }
  __syncthreads();

  s16x8 qf[2];
#pragma unroll
  for (int kf = 0; kf < 2; ++kf) {
    int row = w*16 + q15;
    int idx = (row*64 + kf*32 + g*8) ^ ((row & 7) << 3);
    qf[kf] = *(const s16x8*)&qs[idx];
  }

  float mrun = -1e30f, lrun = 0.f;   // state for q-row l&15
  f32x4 o[4] = {};

  int cur = 0;
  for (int kt = 0; kt < SEQ; kt += 64) {
    if (kt + 64 < SEQ) stage_kv(cur ^ 1, kt + 64);   // prefetch next tile

    // QK^T swapped: sc[ni] = S[k = ni*16 + g*4 + r][q = l&15]
    f32x4 sc[4] = {};
    __builtin_amdgcn_s_setprio(1);
#pragma unroll
    for (int ni = 0; ni < 4; ++ni)
#pragma unroll
      for (int kf = 0; kf < 2; ++kf) {
        int row = ni*16 + q15;
        int idx = (row*64 + kf*32 + g*8) ^ ((row & 7) << 3);
        s16x8 afr = *(const s16x8*)&ks[cur][idx];
        sc[ni] = __builtin_amdgcn_mfma_f32_16x16x32_bf16(afr, qf[kf], sc[ni], 0, 0, 0);
      }
    __builtin_amdgcn_s_setprio(0);

    // lane-local max over 16 scores, then combine the 4 row-copies
    float mt = sc[0][0];
#pragma unroll
    for (int ni = 0; ni < 4; ++ni)
#pragma unroll
      for (int r = 0; r < 4; ++r) mt = fmaxf(mt, sc[ni][r]);
    mt = fmaxf(mt, __shfl_xor(mt, 16));
    mt = fmaxf(mt, __shfl_xor(mt, 32));

    bool need_rescale = __any(mt > mrun + 8.0f);
    float mnew = need_rescale ? fmaxf(mrun, mt) : mrun;

    float p[4][4];
#pragma unroll
    for (int ni = 0; ni < 4; ++ni)
#pragma unroll
      for (int r = 0; r < 4; ++r)
        p[ni][r] = __expf(sc[ni][r] - mnew);

    float s = 0.f;
#pragma unroll
    for (int ni = 0; ni < 4; ++ni)
#pragma unroll
      for (int r = 0; r < 4; ++r) s += p[ni][r];
    s += __shfl_xor(s, 16);
    s += __shfl_xor(s, 32);

    // P -> wave-private LDS (PV A-layout [q][k]), 4x b64, swizzled
#pragma unroll
    for (int ni = 0; ni < 4; ++ni) {
      s16x4 pv;
#pragma unroll
      for (int r = 0; r < 4; ++r) pv[r] = f2bf(p[ni][r]);
      int idx = w*1024 + q15*64 + ((ni*16 + g*4) ^ ((q15 & 7) << 3));
      *(s16x4*)&qs[idx] = pv;
    }

    if (need_rescale) {
      float alpha = __expf(mrun - mnew);
      lrun = lrun * alpha + s;
      mrun = mnew;
      // o rows are g*4+r -> gather those rows' alphas
      float av[4];
#pragma unroll
      for (int r = 0; r < 4; ++r)
        av[r] = __shfl(alpha, (l & 48) | (g*4 + r));
#pragma unroll
      for (int nd = 0; nd < 4; ++nd)
#pragma unroll
        for (int r = 0; r < 4; ++r)
          o[nd][r] *= av[r];
    } else {
      lrun += s;
    }

    asm volatile("s_waitcnt lgkmcnt(0)" ::: "memory");
    __builtin_amdgcn_sched_barrier(0);

    s16x8 pa[2];
#pragma unroll
    for (int kf = 0; kf < 2; ++kf) {
      int idx = w*1024 + q15*64 + ((kf*32 + g*8) ^ ((q15 & 7) << 3));
      pa[kf] = *(const s16x8*)&qs[idx];
    }

    __builtin_amdgcn_s_setprio(1);
#pragma unroll
    for (int nd = 0; nd < 4; ++nd)
#pragma unroll
      for (int kf = 0; kf < 2; ++kf) {
        int row = nd*16 + q15;
        int idx = (row*64 + kf*32 + g*8) ^ ((row & 7) << 3);
        s16x8 bfr = *(const s16x8*)&vs[cur][idx];
        o[nd] = __builtin_amdgcn_mfma_f32_16x16x32_bf16(pa[kf], bfr, o[nd], 0, 0, 0);
      }
    __builtin_amdgcn_s_setprio(0);

    __syncthreads();      // drains prefetch; all waves done with buf[cur]
    cur ^= 1;
  }

  // final normalization: o rows g*4+r need 1/lrun of those rows
  float inv = 1.0f / lrun;
  float iv[4];
#pragma unroll
  for (int r = 0; r < 4; ++r)
    iv[r] = __shfl(inv, (l & 48) | (g*4 + r));

  int b = bh >> 4, h = bh & 15;
#pragma unroll
  for (int nd = 0; nd < 4; ++nd) {
    int dcol = h*DK + nd*16 + q15;
#pragma unroll
    for (int r = 0; r < 4; ++r) {
      int srow = qbase + w*16 + g*4 + r;
      aout[((size_t)(b*SEQ + srow))*DMODEL + dcol] = f2bf(o[nd][r] * iv[r]);
    }
  }
}

// ---------------- host side -------------------------------------------------
extern "C" void kernel_launch(void* const* d_in, const int* in_sizes, int n_in,
                              void* d_out, int out_size, void* d_ws, size_t ws_size,
                              hipStream_t stream) {
  const float* Q  = (const float*)d_in[0];
  const float* K  = (const float*)d_in[1];
  const float* V  = (const float*)d_in[2];
  const float* Wq = (const float*)d_in[3];
  const float* bq = (const float*)d_in[4];
  const float* Wk = (const float*)d_in[5];
  const float* bk = (const float*)d_in[6];
  const float* Wv = (const float*)d_in[7];
  const float* bv = (const float*)d_in[8];
  const float* Wo = (const float*)d_in[9];
  const float* bo = (const float*)d_in[10];

  short* pat;
  hipGetSymbolAddress((void**)&pat, HIP_SYMBOL(g_at));

  const int nX8 = MROWS*DMODEL/8;     // 524288
  const int nW8 = DMODEL*DMODEL/8;    // 131072
  dim3 blk(256);

  cast3<<<dim3(nX8/256, 1, 3), blk, 0, stream>>>(Q, K, V, nX8);
  cast4<<<dim3(nW8/256, 1, 4), blk, 0, stream>>>(Wq, Wk, Wv, Wo, nW8);
  proj_qkv<<<dim3(DMODEL/128, MROWS/128, 3), blk, 0, stream>>>(bq, bk, bv);
  attn_kernel<<<dim3(SEQ/64, BATCH*NHEAD), blk, 0, stream>>>(pat);
  proj_out<<<dim3(DMODEL/128, MROWS/128), blk, 0, stream>>>(bo, (float*)d_out);
}

// Round 4
// 152.703 us; speedup vs baseline: 1.9526x; 1.0723x over previous
//
#include <hip/hip_runtime.h>
#include <hip/hip_bf16.h>

#define DEV __device__ __forceinline__

#define BATCH 2
#define SEQ   2048
#define DMODEL 1024
#define NHEAD 16
#define DK    64
#define MROWS (BATCH*SEQ)   // 4096
#define KD    1024
#define GEMM_NT (KD/32)     // 32 K-iterations

typedef __attribute__((ext_vector_type(4))) float f32x4;
typedef __attribute__((ext_vector_type(8))) short s16x8;
typedef __attribute__((ext_vector_type(4))) short s16x4;
typedef __attribute__((ext_vector_type(4))) float fvec4;

// ---------------- scratch (device globals) ---------------------------------
__device__ short g_X[3][MROWS*DMODEL];   // bf16 Q,K,V inputs
__device__ short g_W[4][DMODEL*DMODEL];  // bf16 Wq,Wk,Wv,Wo
__device__ short g_q [MROWS*DMODEL];     // [B,H,S,dk], pre-scaled by 1/8
__device__ short g_k [MROWS*DMODEL];     // [B,H,S,dk]
__device__ short g_vt[MROWS*DMODEL];     // [B,H,dk,S]
__device__ short g_at[MROWS*DMODEL];     // attention out [B,S,D]

DEV short f2bf(float f) {
  union { __hip_bfloat16 h; short s; } u;
  u.h = __float2bfloat16(f);
  return u.s;
}

DEV void gload_lds16(const void* g, void* l) {
  __builtin_amdgcn_global_load_lds(
      (const __attribute__((address_space(1))) void*)g,
      (__attribute__((address_space(3))) void*)l, 16, 0, 0);
}

// ---------------- fused fp32 -> bf16 casts ---------------------------------
__global__ __launch_bounds__(256) void cast3(const float* __restrict__ a,
                                             const float* __restrict__ b,
                                             const float* __restrict__ c, int n8) {
  const float* src = blockIdx.z == 0 ? a : blockIdx.z == 1 ? b : c;
  short* dst = g_X[blockIdx.z];
  int i = blockIdx.x * 256 + threadIdx.x;
  if (i < n8) {
    const fvec4* p = (const fvec4*)(src + (size_t)i*8);
    fvec4 v0 = p[0], v1 = p[1];
    s16x8 r;
    r[0]=f2bf(v0[0]); r[1]=f2bf(v0[1]); r[2]=f2bf(v0[2]); r[3]=f2bf(v0[3]);
    r[4]=f2bf(v1[0]); r[5]=f2bf(v1[1]); r[6]=f2bf(v1[2]); r[7]=f2bf(v1[3]);
    *(s16x8*)(dst + (size_t)i*8) = r;
  }
}

__global__ __launch_bounds__(256) void cast4(const float* __restrict__ a,
                                             const float* __restrict__ b,
                                             const float* __restrict__ c,
                                             const float* __restrict__ d, int n8) {
  const float* src = blockIdx.z == 0 ? a : blockIdx.z == 1 ? b
                   : blockIdx.z == 2 ? c : d;
  short* dst = g_W[blockIdx.z];
  int i = blockIdx.x * 256 + threadIdx.x;
  if (i < n8) {
    const fvec4* p = (const fvec4*)(src + (size_t)i*8);
    fvec4 v0 = p[0], v1 = p[1];
    s16x8 r;
    r[0]=f2bf(v0[0]); r[1]=f2bf(v0[1]); r[2]=f2bf(v0[2]); r[3]=f2bf(v0[3]);
    r[4]=f2bf(v1[0]); r[5]=f2bf(v1[1]); r[6]=f2bf(v1[2]); r[7]=f2bf(v1[3]);
    *(s16x8*)(dst + (size_t)i*8) = r;
  }
}

// ---------------- GEMM core: C = A[M,K] * B[N,K]^T + bias ------------------
// 128x128 tile, BK=32, 4 waves, TRIPLE-buffered with counted vmcnt (T4):
// per iter exactly one raw s_barrier, wait vmcnt(4) for the tile staged two
// iterations ago while the newer stage's 4 loads stay in flight.
// LDS swizzle: granule XOR ((row>>2)&3)<<3 -> 2-way (free) ds_read_b128.
struct GemmSmem { short As[3][128*32]; short Bs[3][128*32]; };  // 48 KB

DEV void gemm_core(GemmSmem& sm, const short* __restrict__ A,
                   const short* __restrict__ Bw, const float* __restrict__ bias,
                   void* __restrict__ outp, float scale, int mode,
                   int rowBase, int colBase) {
  const int t = threadIdx.x, l = t & 63, w = t >> 6, g = l >> 4;
  const int wr = w >> 1, wc = w & 1;

  f32x4 acc[4][4] = {};

  auto stage = [&](int buf, int k0) {
#pragma unroll
    for (int j = 0; j < 2; ++j) {
      int e = w*1024 + j*512 + l*8;
      int e2 = e ^ (((e >> 7) & 3) << 3);      // pre-swizzled source (granule bits)
      int r = e2 >> 5, c = e2 & 31;
      gload_lds16(A  + (size_t)(rowBase + r)*KD + k0 + c, &sm.As[buf][w*1024 + j*512]);
      gload_lds16(Bw + (size_t)(colBase + r)*KD + k0 + c, &sm.Bs[buf][w*1024 + j*512]);
    }
  };

  stage(0, 0);
  stage(1, 32);

  int cur = 0, nxt = 2;
  for (int i = 0; i < GEMM_NT; ++i) {
    // wait for tile i's stage (issued 2 iters ago); allow newest 4 in flight
    if (i < GEMM_NT - 1) asm volatile("s_waitcnt vmcnt(4)" ::: "memory");
    else                 asm volatile("s_waitcnt vmcnt(0)" ::: "memory");
    __builtin_amdgcn_s_barrier();
    __builtin_amdgcn_sched_barrier(0);

    s16x8 a[4], b[4];
#pragma unroll
    for (int x = 0; x < 4; ++x) {
      int ra = wr*64 + x*16 + (l & 15);
      int ia = (ra*32 + g*8) ^ (((ra >> 2) & 3) << 3);
      a[x] = *(const s16x8*)&sm.As[cur][ia];
      int rb = wc*64 + x*16 + (l & 15);
      int ib = (rb*32 + g*8) ^ (((rb >> 2) & 3) << 3);
      b[x] = *(const s16x8*)&sm.Bs[cur][ib];
    }
    if (i + 2 < GEMM_NT) stage(nxt, (i + 2)*32);   // deep prefetch
    __builtin_amdgcn_sched_barrier(0);

    __builtin_amdgcn_s_setprio(1);
#pragma unroll
    for (int x = 0; x < 4; ++x)
#pragma unroll
      for (int jn = 0; jn < 4; ++jn)
        acc[x][jn] = __builtin_amdgcn_mfma_f32_16x16x32_bf16(a[x], b[jn], acc[x][jn], 0, 0, 0);
    __builtin_amdgcn_s_setprio(0);

    cur = cur == 2 ? 0 : cur + 1;
    nxt = nxt == 2 ? 0 : nxt + 1;
  }

  // epilogue: C/D layout col = l&15, row = (l>>4)*4 + r
#pragma unroll
  for (int x = 0; x < 4; ++x) {
    int mrow0 = rowBase + wr*64 + x*16 + g*4;
#pragma unroll
    for (int jn = 0; jn < 4; ++jn) {
      int n = colBase + wc*64 + jn*16 + (l & 15);
      float bv = bias[n];
#pragma unroll
      for (int r = 0; r < 4; ++r) {
        int m = mrow0 + r;
        float val = (acc[x][jn][r] + bv) * scale;
        if (mode == 1) {
          int b = m >> 11, s = m & 2047, h = n >> 6, d = n & 63;
          ((short*)outp)[(((size_t)(b*NHEAD + h)*SEQ + s)*DK) + d] = f2bf(val);
        } else if (mode == 2) {
          int b = m >> 11, s = m & 2047, h = n >> 6, d = n & 63;
          ((short*)outp)[((size_t)(b*NHEAD + h)*DK + d)*SEQ + s] = f2bf(val);
        } else {
          ((float*)outp)[(size_t)m*DMODEL + n] = val;
        }
      }
    }
  }
}

// fused Q/K/V projections: grid (8, 32, 3); XCD-swizzled tile mapping
__global__ __launch_bounds__(256, 3)
void proj_qkv(const float* __restrict__ bq, const float* __restrict__ bk,
              const float* __restrict__ bv) {
  __shared__ GemmSmem sm;
  int z = blockIdx.z;
  int orig = blockIdx.y*8 + blockIdx.x;          // 256 per z, 256%8==0
  int swz = (orig & 7)*32 + (orig >> 3);         // bijective chunked
  int bx = swz & 7, by = swz >> 3;
  const float* bias = z == 0 ? bq : z == 1 ? bk : bv;
  void* outp = z == 0 ? (void*)g_q : z == 1 ? (void*)g_k : (void*)g_vt;
  gemm_core(sm, g_X[z], g_W[z], bias, outp, z == 0 ? 0.125f : 1.0f,
            z == 2 ? 2 : 1, by*128, bx*128);
}

__global__ __launch_bounds__(256, 3)
void proj_out(const float* __restrict__ bo, float* __restrict__ out) {
  __shared__ GemmSmem sm;
  int orig = blockIdx.y*8 + blockIdx.x;
  int swz = (orig & 7)*32 + (orig >> 3);
  int bx = swz & 7, by = swz >> 3;
  gemm_core(sm, g_at, g_W[3], bo, out, 1.0f, 3, by*128, bx*128);
}

// ---------------- flash attention (swapped QK^T, lane-local softmax) --------
// grid (S/64, B*H). 4 waves, 16 q-rows each. KBLK=64, double-buffered K/V.
// Counted-wait pipeline: stage(next) at top, compute covers latency,
// vmcnt(0) + raw s_barrier at bottom (no full drain before compute).
__global__ __launch_bounds__(256, 4)
void attn_kernel(short* __restrict__ aout) {
  __shared__ short qs[64*64];       // rows w*16..: wave-private; reused as P
  __shared__ short ks[2][64*64];
  __shared__ short vs[2][64*64];

  const int t = threadIdx.x, l = t & 63, w = t >> 6, g = l >> 4;
  const int q15 = l & 15;
  int orig = blockIdx.y*32 + blockIdx.x;     // 1024 blocks, %8==0
  int swz = (orig & 7)*128 + (orig >> 3);    // 4 heads' K/V per XCD L2
  const int qblk = swz & 31, bh = swz >> 5;
  const int qbase = qblk * 64;
  const size_t hoff = (size_t)bh * SEQ * DK;

  auto stage_kv = [&](int buf, int kt) {
#pragma unroll
    for (int j = 0; j < 2; ++j) {
      int e = w*1024 + j*512 + l*8;
      int e2 = e ^ (((e >> 6) & 7) << 3);
      gload_lds16(g_k + hoff + (size_t)kt*DK + e2, &ks[buf][w*1024 + j*512]);
      gload_lds16(g_vt + hoff + (size_t)(e2 >> 6)*SEQ + kt + (e2 & 63),
                  &vs[buf][w*1024 + j*512]);
    }
  };

  { // prologue: stage Q + first K/V tile, full drain once
#pragma unroll
    for (int j = 0; j < 2; ++j) {
      int e = w*1024 + j*512 + l*8;
      int e2 = e ^ (((e >> 6) & 7) << 3);
      gload_lds16(g_q + hoff + (size_t)qbase*DK + e2, &qs[w*1024 + j*512]);
    }
    stage_kv(0, 0);
  }
  __syncthreads();

  s16x8 qf[2];
#pragma unroll
  for (int kf = 0; kf < 2; ++kf) {
    int row = w*16 + q15;
    int idx = (row*64 + kf*32 + g*8) ^ ((row & 7) << 3);
    qf[kf] = *(const s16x8*)&qs[idx];
  }

  float mrun = -1e30f, lrun = 0.f;   // state for q-row l&15
  f32x4 o[4] = {};

  int cur = 0;
  for (int kt = 0; kt < SEQ; kt += 64) {
    if (kt + 64 < SEQ) stage_kv(cur ^ 1, kt + 64);   // issue early

    // QK^T swapped: sc[ni] = S[k = ni*16 + g*4 + r][q = l&15]
    f32x4 sc[4] = {};
    __builtin_amdgcn_s_setprio(1);
#pragma unroll
    for (int ni = 0; ni < 4; ++ni)
#pragma unroll
      for (int kf = 0; kf < 2; ++kf) {
        int row = ni*16 + q15;
        int idx = (row*64 + kf*32 + g*8) ^ ((row & 7) << 3);
        s16x8 afr = *(const s16x8*)&ks[cur][idx];
        sc[ni] = __builtin_amdgcn_mfma_f32_16x16x32_bf16(afr, qf[kf], sc[ni], 0, 0, 0);
      }
    __builtin_amdgcn_s_setprio(0);

    // lane-local max (balanced tree) + 2 shfl for the 4 row-copies
    float m0 = fmaxf(fmaxf(sc[0][0], sc[0][1]), fmaxf(sc[0][2], sc[0][3]));
    float m1 = fmaxf(fmaxf(sc[1][0], sc[1][1]), fmaxf(sc[1][2], sc[1][3]));
    float m2 = fmaxf(fmaxf(sc[2][0], sc[2][1]), fmaxf(sc[2][2], sc[2][3]));
    float m3 = fmaxf(fmaxf(sc[3][0], sc[3][1]), fmaxf(sc[3][2], sc[3][3]));
    float mt = fmaxf(fmaxf(m0, m1), fmaxf(m2, m3));
    mt = fmaxf(mt, __shfl_xor(mt, 16));
    mt = fmaxf(mt, __shfl_xor(mt, 32));

    bool need_rescale = __any(mt > mrun + 8.0f);
    float mnew = need_rescale ? fmaxf(mrun, mt) : mrun;

    float p[4][4];
#pragma unroll
    for (int ni = 0; ni < 4; ++ni)
#pragma unroll
      for (int r = 0; r < 4; ++r)
        p[ni][r] = __expf(sc[ni][r] - mnew);

    float s0 = (p[0][0]+p[0][1]) + (p[0][2]+p[0][3]);
    float s1 = (p[1][0]+p[1][1]) + (p[1][2]+p[1][3]);
    float s2 = (p[2][0]+p[2][1]) + (p[2][2]+p[2][3]);
    float s3 = (p[3][0]+p[3][1]) + (p[3][2]+p[3][3]);
    float s = (s0+s1) + (s2+s3);
    s += __shfl_xor(s, 16);
    s += __shfl_xor(s, 32);

    // P -> wave-private LDS (PV A-layout [q][k]), 4x b64, swizzled
#pragma unroll
    for (int ni = 0; ni < 4; ++ni) {
      s16x4 pv;
#pragma unroll
      for (int r = 0; r < 4; ++r) pv[r] = f2bf(p[ni][r]);
      int idx = w*1024 + q15*64 + ((ni*16 + g*4) ^ ((q15 & 7) << 3));
      *(s16x4*)&qs[idx] = pv;
    }

    if (need_rescale) {
      float alpha = __expf(mrun - mnew);
      lrun = lrun * alpha + s;
      mrun = mnew;
      float av[4];
#pragma unroll
      for (int r = 0; r < 4; ++r)
        av[r] = __shfl(alpha, (l & 48) | (g*4 + r));
#pragma unroll
      for (int nd = 0; nd < 4; ++nd)
#pragma unroll
        for (int r = 0; r < 4; ++r)
          o[nd][r] *= av[r];
    } else {
      lrun += s;
    }

    asm volatile("s_waitcnt lgkmcnt(0)" ::: "memory");
    __builtin_amdgcn_sched_barrier(0);

    s16x8 pa[2];
#pragma unroll
    for (int kf = 0; kf < 2; ++kf) {
      int idx = w*1024 + q15*64 + ((kf*32 + g*8) ^ ((q15 & 7) << 3));
      pa[kf] = *(const s16x8*)&qs[idx];
    }

    __builtin_amdgcn_s_setprio(1);
#pragma unroll
    for (int nd = 0; nd < 4; ++nd)
#pragma unroll
      for (int kf = 0; kf < 2; ++kf) {
        int row = nd*16 + q15;
        int idx = (row*64 + kf*32 + g*8) ^ ((row & 7) << 3);
        s16x8 bfr = *(const s16x8*)&vs[cur][idx];
        o[nd] = __builtin_amdgcn_mfma_f32_16x16x32_bf16(pa[kf], bfr, o[nd], 0, 0, 0);
      }
    __builtin_amdgcn_s_setprio(0);

    // counted-wait: only our own 4 prefetch loads are outstanding
    asm volatile("s_waitcnt vmcnt(0)" ::: "memory");
    __builtin_amdgcn_s_barrier();
    __builtin_amdgcn_sched_barrier(0);
    cur ^= 1;
  }

  // final normalization: o rows g*4+r need 1/lrun of those rows
  float inv = 1.0f / lrun;
  float iv[4];
#pragma unroll
  for (int r = 0; r < 4; ++r)
    iv[r] = __shfl(inv, (l & 48) | (g*4 + r));

  int b = bh >> 4, h = bh & 15;
#pragma unroll
  for (int nd = 0; nd < 4; ++nd) {
    int dcol = h*DK + nd*16 + q15;
#pragma unroll
    for (int r = 0; r < 4; ++r) {
      int srow = qbase + w*16 + g*4 + r;
      aout[((size_t)(b*SEQ + srow))*DMODEL + dcol] = f2bf(o[nd][r] * iv[r]);
    }
  }
}

// ---------------- host side -------------------------------------------------
extern "C" void kernel_launch(void* const* d_in, const int* in_sizes, int n_in,
                              void* d_out, int out_size, void* d_ws, size_t ws_size,
                              hipStream_t stream) {
  const float* Q  = (const float*)d_in[0];
  const float* K  = (const float*)d_in[1];
  const float* V  = (const float*)d_in[2];
  const float* Wq = (const float*)d_in[3];
  const float* bq = (const float*)d_in[4];
  const float* Wk = (const float*)d_in[5];
  const float* bk = (const float*)d_in[6];
  const float* Wv = (const float*)d_in[7];
  const float* bv = (const float*)d_in[8];
  const float* Wo = (const float*)d_in[9];
  const float* bo = (const float*)d_in[10];

  short* pat;
  hipGetSymbolAddress((void**)&pat, HIP_SYMBOL(g_at));

  const int nX8 = MROWS*DMODEL/8;     // 524288
  const int nW8 = DMODEL*DMODEL/8;    // 131072
  dim3 blk(256);

  cast3<<<dim3(nX8/256, 1, 3), blk, 0, stream>>>(Q, K, V, nX8);
  cast4<<<dim3(nW8/256, 1, 4), blk, 0, stream>>>(Wq, Wk, Wv, Wo, nW8);
  proj_qkv<<<dim3(DMODEL/128, MROWS/128, 3), blk, 0, stream>>>(bq, bk, bv);
  attn_kernel<<<dim3(SEQ/64, BATCH*NHEAD), blk, 0, stream>>>(pat);
  proj_out<<<dim3(DMODEL/128, MROWS/128), blk, 0, stream>>>(bo, (float*)d_out);
}